// Round 3
// baseline (2112.803 us; speedup 1.0000x reference)
//
#include <hip/hip_runtime.h>
#include <hip/hip_bf16.h>
#include <stdint.h>

typedef unsigned short ushort_t;
typedef __bf16 bf16x8 __attribute__((ext_vector_type(8)));
typedef float f32x4 __attribute__((ext_vector_type(4)));
typedef unsigned long long u64;

#define T_STEPS 196

// ---- workspace layout (bytes) ----
#define O_WPACK 0u
#define SZ_WPACK (2u*2048u*1024u*2u)            // packed [Wih|Whh] bf16, 8 MB
#define O_WFC   (O_WPACK + SZ_WPACK)
#define SZ_WFC  (5120u*512u*2u)                 // W_fc bf16 padded to 5120 rows
#define O_BIAS  (O_WFC + SZ_WFC)
#define SZ_BIAS (2u*2048u*4u)                   // b_ih + b_hh, f32
#define O_SEQT  (O_BIAS + SZ_BIAS)
#define SZ_SEQT (196u*64u*512u*2u)              // x transposed -> [t][b][i] bf16
#define O_H     (O_SEQT + SZ_SEQT)
#define SZ_H    (2u*196u*64u*512u*2u)           // h_all[layer][t][b][h] bf16

// xp scratch lives in d_out (written before fc_gemm overwrites d_out):
// layout [t][bs(4)][gs(32)][batch 16][gate-row 64] f32 = 102.8 MB < 251 MB

// scan LDS: weights [64][1032] + in [16][520] + gates [64][17] f32
#define SCAN_LDS_BYTES (64*1032*2 + 16*520*2 + 64*17*4)   // 153,088 B

__device__ __forceinline__ ushort_t f2bf(float v) {
  __hip_bfloat16 h = __float2bfloat16(v);
  return __builtin_bit_cast(ushort_t, h);
}
__device__ __forceinline__ u64 ald64(const void* p) {
  return __hip_atomic_load((const u64*)p, __ATOMIC_RELAXED, __HIP_MEMORY_SCOPE_AGENT);
}
__device__ __forceinline__ bool valid64(u64 v) {
  return ((unsigned)v != 0xFFFFFFFFu) && ((unsigned)(v >> 32) != 0xFFFFFFFFu);
}
__device__ __forceinline__ float sigm(float x) {
  return __builtin_amdgcn_rcpf(1.f + __expf(-x));
}
__device__ __forceinline__ float tanh_f(float x) {
  return 1.f - 2.f * __builtin_amdgcn_rcpf(1.f + __expf(2.f * x));
}

// ---------------- prep: cast/pack weights, biases ----------------
__global__ __launch_bounds__(256) void prep_pack(
    const float* __restrict__ Wih0, const float* __restrict__ Whh0,
    const float* __restrict__ bih0, const float* __restrict__ bhh0,
    const float* __restrict__ Wih1, const float* __restrict__ Whh1,
    const float* __restrict__ bih1, const float* __restrict__ bhh1,
    const float* __restrict__ Wfc,
    ushort_t* __restrict__ wpack, ushort_t* __restrict__ wfcp,
    float* __restrict__ bias)
{
  const size_t NW_ = 2u*2048u*1024u;   // 4,194,304
  const size_t NF  = 5120u*512u;       // 2,621,440
  const size_t NB  = 2u*2048u;
  const size_t TOT = NW_ + NF + NB;
  for (size_t idx = (size_t)blockIdx.x*256 + threadIdx.x; idx < TOT;
       idx += (size_t)gridDim.x*256) {
    if (idx < NW_) {
      int l   = (int)(idx >> 21);
      int rem = (int)(idx & ((1u<<21)-1));
      int r = rem >> 10, k = rem & 1023;
      const float* src = (k < 512) ? (l ? Wih1 : Wih0) : (l ? Whh1 : Whh0);
      wpack[idx] = f2bf(src[(size_t)r*512 + (k & 511)]);
    } else if (idx < NW_ + NF) {
      size_t i2 = idx - NW_;
      int n = (int)(i2 >> 9), k = (int)(i2 & 511);
      wfcp[i2] = (n < 5000) ? f2bf(Wfc[(size_t)n*512 + k]) : (ushort_t)0;
    } else {
      size_t i2 = idx - NW_ - NF;
      int l = (int)(i2 >> 11), r = (int)(i2 & 2047);
      bias[i2] = l ? (bih1[r] + bhh1[r]) : (bih0[r] + bhh0[r]);
    }
  }
}

// ---------------- prep: x (64,512,196) f32 -> seqT [196][64][512] bf16 ----------------
__global__ __launch_bounds__(256) void prep_seq(const float* __restrict__ x,
                                                ushort_t* __restrict__ seqT)
{
  __shared__ float tile[64 * 197];
  int b = blockIdx.x >> 3, ic = blockIdx.x & 7;
  const float* src = x + ((size_t)b*512 + ic*64) * 196;
  for (int it = 0; it < 49; ++it) {              // 64*196 = 49*256
    int idx = threadIdx.x + it*256;
    int row = idx / 196, t = idx % 196;
    tile[row*197 + t] = src[idx];
  }
  __syncthreads();
  for (int it = 0; it < 49; ++it) {
    int idx = threadIdx.x + it*256;
    int t = idx >> 6, ii = idx & 63;
    seqT[(size_t)t*(64*512) + (size_t)b*512 + ic*64 + ii] = f2bf(tile[ii*197 + t]);
  }
}

// ---------------- xp GEMM: xp = Wih0 @ x_t + (bih0+bhh0), scan-layout f32 ----------------
// M = 2048 gates (grid.x = 16), N = 12544 t*64+b (grid.y = 98), K = 512
__global__ __launch_bounds__(256, 2) void xp_gemm(
    const ushort_t* __restrict__ wih,   // wpack layer0, ld 1024 (cols 0..511)
    const ushort_t* __restrict__ xseq,  // seqT [12544][512]
    const float* __restrict__ bias,     // [2048] layer-0 b_ih+b_hh
    float* __restrict__ xp)
{
  __shared__ ushort_t As[128*32];
  __shared__ ushort_t Bs[128*32];
  const int tid = threadIdx.x;
  const int wvid = tid >> 6, lane = tid & 63;
  const int lr = lane & 15, lg = lane >> 4;
  const int wr = wvid >> 1, wc = wvid & 1;
  const int m0 = blockIdx.x * 128, n0 = blockIdx.y * 128;

  f32x4 acc[4][4];
  #pragma unroll
  for (int i = 0; i < 4; ++i)
    #pragma unroll
    for (int j = 0; j < 4; ++j)
      acc[i][j] = (f32x4){0.f, 0.f, 0.f, 0.f};

  for (int kt = 0; kt < 16; ++kt) {
    #pragma unroll
    for (int c = 0; c < 2; ++c) {
      int chb = wvid*128 + c*64;
      int ch = chb + lane;
      int m = ch >> 2, kh = ch & 3;
      const ushort_t* ga = wih + (size_t)(m0 + m)*1024 + kt*32 + kh*8;
      __builtin_amdgcn_global_load_lds(
          (const __attribute__((address_space(1))) void*)ga,
          (__attribute__((address_space(3))) void*)&As[chb*8], 16, 0, 0);
      const ushort_t* gb = xseq + (size_t)(n0 + m)*512 + kt*32 + kh*8;
      __builtin_amdgcn_global_load_lds(
          (const __attribute__((address_space(1))) void*)gb,
          (__attribute__((address_space(3))) void*)&Bs[chb*8], 16, 0, 0);
    }
    asm volatile("s_waitcnt vmcnt(0)" ::: "memory");
    __syncthreads();

    bf16x8 af[4], bf_[4];
    #pragma unroll
    for (int i = 0; i < 4; ++i)
      af[i] = *(const bf16x8*)&As[(wr*64 + i*16 + lr)*32 + lg*8];
    #pragma unroll
    for (int j = 0; j < 4; ++j)
      bf_[j] = *(const bf16x8*)&Bs[(wc*64 + j*16 + lr)*32 + lg*8];
    #pragma unroll
    for (int i = 0; i < 4; ++i)
      #pragma unroll
      for (int j = 0; j < 4; ++j)
        acc[i][j] = __builtin_amdgcn_mfma_f32_16x16x32_bf16(af[i], bf_[j], acc[i][j], 0, 0, 0);
    __syncthreads();
  }

  // epilogue: scatter to xp[t][bs][gs][b&15][gate-row 64] with bias
  #pragma unroll
  for (int i = 0; i < 4; ++i) {
    int g0 = m0 + wr*64 + i*16 + lg*4;      // 4 consecutive gates
    f32x4 b4 = *(const f32x4*)&bias[g0];
    int q = g0 >> 9, u = g0 & 511;
    int gsl = u >> 4, j0 = u & 15;          // j0 = lg*4
    #pragma unroll
    for (int j = 0; j < 4; ++j) {
      int n = n0 + wc*64 + j*16 + lr;
      int t = n >> 6, b = n & 63;
      size_t idx = (((size_t)t*4 + (b>>4))*32 + gsl)*1024 + (size_t)(b&15)*64 + q*16 + j0;
      *(f32x4*)&xp[idx] = acc[i][j] + b4;
    }
  }
}

// ---------------- fused 2-layer LSTM scan (weight-stationary, sentinel sync) ----------------
// grid = 256 wgs: layer(2) x bslice(4, 16 batch each) x gslice(32, 16 h-dims each)
// All cross-wg h traffic: relaxed agent-scope atomics; h_all pre-set to 0xFF sentinel.
__global__ __launch_bounds__(256, 1) void lstm_scan(
    const ushort_t* __restrict__ wpack, const float* __restrict__ bias,
    ushort_t* __restrict__ h_all, const float* __restrict__ xp)
{
  extern __shared__ char smem[];
  ushort_t* w_s  = (ushort_t*)smem;                          // [64][1032]
  ushort_t* in_s = (ushort_t*)(smem + 64*1032*2);            // [16][520]
  float*    g_s  = (float*)(smem + 64*1032*2 + 16*520*2);    // [64][17]

  const int wg = blockIdx.x;
  const int layer = wg >> 7;
  const int bs = (wg >> 5) & 3;
  const int gs = wg & 31;
  const int tid = threadIdx.x;
  const int wv = tid >> 6;
  const int lane = tid & 63;
  const int lr = lane & 15;
  const int lg = lane >> 4;

  // weight slice: rows r = 512*q + gs*16 + j  (q = gate, j = h-dim within slice)
  const ushort_t* wbase = wpack + (size_t)layer * (2048*1024);
  if (layer == 0) {              // only W_hh needed (x-part hoisted to xp_gemm)
    for (int ch = tid; ch < 4096; ch += 256) {
      int row = ch >> 6, kc = 64 + (ch & 63);
      int q = row >> 4, j = row & 15;
      const ushort_t* g = wbase + (size_t)(512*q + gs*16 + j)*1024 + kc*8;
      *(uint4*)&w_s[row*1032 + kc*8] = *(const uint4*)g;
    }
  } else {
    for (int ch = tid; ch < 8192; ch += 256) {
      int row = ch >> 7, kc = ch & 127;
      int q = row >> 4, j = row & 15;
      const ushort_t* g = wbase + (size_t)(512*q + gs*16 + j)*1024 + kc*8;
      *(uint4*)&w_s[row*1032 + kc*8] = *(const uint4*)g;
    }
  }

  const int b_loc = tid >> 4;   // batch within slice
  const int hd    = tid & 15;   // h-dim within slice
  const float b_i = bias[layer*2048 +    0 + gs*16 + hd];   // used by layer 1 only
  const float b_f = bias[layer*2048 +  512 + gs*16 + hd];
  const float b_g = bias[layer*2048 + 1024 + gs*16 + hd];
  const float b_o = bias[layer*2048 + 1536 + gs*16 + hd];

  ushort_t* hout = h_all + (size_t)layer * (196*64*512);
  const ushort_t* hdep = h_all;                    // layer-0 output stream

  float c_reg = 0.f;
  const int wrow = (wv*16 + lr) * 1032;
  const int brow = lr * 520;
  const int koff = lg * 8;
  // xp per-thread pointer (layer 0): [t][bs][gs][lr][wv*16+lg*4]
  const float* xq = xp + ((size_t)bs*32 + gs)*1024 + (size_t)lr*64 + wv*16 + lg*4;

  for (int t = 0; t < T_STEPS; ++t) {
    f32x4 acc_a = {0.f,0.f,0.f,0.f}, acc_b = {0.f,0.f,0.f,0.f};

    if (layer == 0) {
      acc_a = *(const f32x4*)&xq[(size_t)t*131072];   // x-part + bias, precomputed
      if (t > 0) {
        const ushort_t* hsrc = hout + ((size_t)(t-1)*64 + bs*16) * 512;
        u64 v[8];
        int guard = 200000;
        for (;;) {
          #pragma unroll
          for (int it = 0; it < 8; ++it) {
            int ch = tid + it*256; int row = ch >> 7, kc = ch & 127;
            v[it] = ald64(&hsrc[row*512 + kc*4]);
          }
          bool ok = true;
          #pragma unroll
          for (int it = 0; it < 8; ++it) ok &= valid64(v[it]);
          if (ok || --guard == 0) break;
        }
        #pragma unroll
        for (int it = 0; it < 8; ++it) {
          int ch = tid + it*256; int row = ch >> 7, kc = ch & 127;
          *(u64*)&in_s[row*520 + kc*4] = v[it];
        }
      }
      __syncthreads();                               // bar A
      if (t > 0) {
        #pragma unroll
        for (int ks = 0; ks < 8; ++ks) {
          bf16x8 a = *(const bf16x8*)&w_s[wrow + 512 + ks*32 + koff];
          bf16x8 bb = *(const bf16x8*)&in_s[brow + ks*32 + koff];
          acc_a = __builtin_amdgcn_mfma_f32_16x16x32_bf16(a, bb, acc_a, 0, 0, 0);
        }
        #pragma unroll
        for (int ks = 8; ks < 16; ++ks) {
          bf16x8 a = *(const bf16x8*)&w_s[wrow + 512 + ks*32 + koff];
          bf16x8 bb = *(const bf16x8*)&in_s[brow + ks*32 + koff];
          acc_b = __builtin_amdgcn_mfma_f32_16x16x32_bf16(a, bb, acc_b, 0, 0, 0);
        }
      }
    } else {
      // issue h1(t-1) fragment loads early (hide under h0 poll + x-MFMA)
      u64 f0[16], f1[16];
      const ushort_t* hp = hout + ((size_t)(t-1)*64 + bs*16) * 512;
      if (t > 0) {
        #pragma unroll
        for (int ks = 0; ks < 16; ++ks) {
          f0[ks] = ald64(&hp[lr*512 + ks*32 + lg*8]);
          f1[ks] = ald64(&hp[lr*512 + ks*32 + lg*8 + 4]);
        }
      }
      // sentinel-stage h0[t]
      {
        const ushort_t* xsrc = hdep + ((size_t)t*64 + bs*16) * 512;
        u64 v[8];
        int guard = 200000;
        for (;;) {
          #pragma unroll
          for (int it = 0; it < 8; ++it) {
            int ch = tid + it*256; int row = ch >> 7, kc = ch & 127;
            v[it] = ald64(&xsrc[row*512 + kc*4]);
          }
          bool ok = true;
          #pragma unroll
          for (int it = 0; it < 8; ++it) ok &= valid64(v[it]);
          if (ok || --guard == 0) break;
        }
        #pragma unroll
        for (int it = 0; it < 8; ++it) {
          int ch = tid + it*256; int row = ch >> 7, kc = ch & 127;
          *(u64*)&in_s[row*520 + kc*4] = v[it];
        }
      }
      __syncthreads();                               // bar A
      #pragma unroll
      for (int ks = 0; ks < 8; ++ks) {               // W_ih1 * h0[t]
        bf16x8 a = *(const bf16x8*)&w_s[wrow + ks*32 + koff];
        bf16x8 bb = *(const bf16x8*)&in_s[brow + ks*32 + koff];
        acc_a = __builtin_amdgcn_mfma_f32_16x16x32_bf16(a, bb, acc_a, 0, 0, 0);
      }
      #pragma unroll
      for (int ks = 8; ks < 16; ++ks) {
        bf16x8 a = *(const bf16x8*)&w_s[wrow + ks*32 + koff];
        bf16x8 bb = *(const bf16x8*)&in_s[brow + ks*32 + koff];
        acc_b = __builtin_amdgcn_mfma_f32_16x16x32_bf16(a, bb, acc_b, 0, 0, 0);
      }
      if (t > 0) {
        int guard = 200000;                          // verify frags, retry if stale
        for (;;) {
          bool ok = true;
          #pragma unroll
          for (int ks = 0; ks < 16; ++ks) ok &= valid64(f0[ks]) && valid64(f1[ks]);
          if (ok || --guard == 0) break;
          #pragma unroll
          for (int ks = 0; ks < 16; ++ks) {
            f0[ks] = ald64(&hp[lr*512 + ks*32 + lg*8]);
            f1[ks] = ald64(&hp[lr*512 + ks*32 + lg*8 + 4]);
          }
        }
        #pragma unroll
        for (int ks = 0; ks < 8; ++ks) {             // W_hh1 * h1(t-1)
          bf16x8 a = *(const bf16x8*)&w_s[wrow + 512 + ks*32 + koff];
          ulonglong2 p; p.x = f0[ks]; p.y = f1[ks];
          bf16x8 bb = __builtin_bit_cast(bf16x8, p);
          acc_a = __builtin_amdgcn_mfma_f32_16x16x32_bf16(a, bb, acc_a, 0, 0, 0);
        }
        #pragma unroll
        for (int ks = 8; ks < 16; ++ks) {
          bf16x8 a = *(const bf16x8*)&w_s[wrow + 512 + ks*32 + koff];
          ulonglong2 p; p.x = f0[ks]; p.y = f1[ks];
          bf16x8 bb = __builtin_bit_cast(bf16x8, p);
          acc_b = __builtin_amdgcn_mfma_f32_16x16x32_bf16(a, bb, acc_b, 0, 0, 0);
        }
      }
    }

    f32x4 accf = acc_a + acc_b;
    #pragma unroll
    for (int j2 = 0; j2 < 4; ++j2)
      g_s[(wv*16 + lg*4 + j2)*17 + lr] = accf[j2];
    __syncthreads();                                 // bar B

    // elementwise cell update: one (hd, b) pair per thread
    float gi = g_s[(  0 + hd)*17 + b_loc];
    float gf = g_s[( 16 + hd)*17 + b_loc];
    float gg = g_s[( 32 + hd)*17 + b_loc];
    float go = g_s[( 48 + hd)*17 + b_loc];
    if (layer == 1) { gi += b_i; gf += b_f; gg += b_g; go += b_o; }
    float si = sigm(gi);
    float sf = sigm(gf);
    float tg = tanh_f(gg);
    float so = sigm(go);
    c_reg = sf*c_reg + si*tg;
    float hv = so * tanh_f(c_reg);

    unsigned int hb = (unsigned int)f2bf(hv);
    unsigned int other = __shfl_xor(hb, 1);
    if ((tid & 1) == 0) {
      unsigned int packed = hb | (other << 16);      // never 0xFFFFFFFF (|h|<1)
      __hip_atomic_store(
          (unsigned int*)&hout[((size_t)t*64 + bs*16 + b_loc)*512 + gs*16 + hd],
          packed, __ATOMIC_RELAXED, __HIP_MEMORY_SCOPE_AGENT);
    }
    // no drain barrier: consumers detect via sentinel
  }
}

// ---------------- FC: out[b][t][v] = h1[t*64+b] . wfc[v] + bfc[v] ----------------
__global__ __launch_bounds__(256, 2) void fc_gemm(
    const ushort_t* __restrict__ h1,    // [12544][512] bf16
    const ushort_t* __restrict__ wfc,   // [5120][512] bf16 (padded)
    const float* __restrict__ bfc,      // [5000]
    float* __restrict__ out)            // [64][196][5000]
{
  __shared__ ushort_t As[128*32];
  __shared__ ushort_t Bs[128*32];
  const int tid = threadIdx.x;
  const int wvid = tid >> 6, lane = tid & 63;
  const int lr = lane & 15, lg = lane >> 4;
  const int wr = wvid >> 1, wc = wvid & 1;
  const int m0 = blockIdx.x * 128, n0 = blockIdx.y * 128;

  f32x4 acc[4][4];
  #pragma unroll
  for (int i = 0; i < 4; ++i)
    #pragma unroll
    for (int j = 0; j < 4; ++j)
      acc[i][j] = (f32x4){0.f, 0.f, 0.f, 0.f};

  for (int kt = 0; kt < 16; ++kt) {
    #pragma unroll
    for (int c = 0; c < 2; ++c) {
      int chb = wvid*128 + c*64;
      int ch = chb + lane;
      int m = ch >> 2, kh = ch & 3;
      const ushort_t* ga = h1  + (size_t)(m0 + m)*512 + kt*32 + kh*8;
      __builtin_amdgcn_global_load_lds(
          (const __attribute__((address_space(1))) void*)ga,
          (__attribute__((address_space(3))) void*)&As[chb*8], 16, 0, 0);
      const ushort_t* gb = wfc + (size_t)(n0 + m)*512 + kt*32 + kh*8;
      __builtin_amdgcn_global_load_lds(
          (const __attribute__((address_space(1))) void*)gb,
          (__attribute__((address_space(3))) void*)&Bs[chb*8], 16, 0, 0);
    }
    asm volatile("s_waitcnt vmcnt(0)" ::: "memory");
    __syncthreads();

    bf16x8 af[4], bf_[4];
    #pragma unroll
    for (int i = 0; i < 4; ++i)
      af[i] = *(const bf16x8*)&As[(wr*64 + i*16 + lr)*32 + lg*8];
    #pragma unroll
    for (int j = 0; j < 4; ++j)
      bf_[j] = *(const bf16x8*)&Bs[(wc*64 + j*16 + lr)*32 + lg*8];
    #pragma unroll
    for (int i = 0; i < 4; ++i)
      #pragma unroll
      for (int j = 0; j < 4; ++j)
        acc[i][j] = __builtin_amdgcn_mfma_f32_16x16x32_bf16(af[i], bf_[j], acc[i][j], 0, 0, 0);
    __syncthreads();
  }

  #pragma unroll
  for (int j = 0; j < 4; ++j) {
    int coln = n0 + wc*64 + j*16 + lr;
    if (coln >= 5000) continue;
    float bb = bfc[coln];
    #pragma unroll
    for (int i = 0; i < 4; ++i) {
      #pragma unroll
      for (int jj = 0; jj < 4; ++jj) {
        int rowm = m0 + wr*64 + i*16 + lg*4 + jj;
        int tt = rowm >> 6, b2 = rowm & 63;
        out[(size_t)b2*980000 + (size_t)tt*5000 + coln] = acc[i][j][jj] + bb;
      }
    }
  }
}

extern "C" void kernel_launch(void* const* d_in, const int* in_sizes, int n_in,
                              void* d_out, int out_size, void* d_ws, size_t ws_size,
                              hipStream_t stream) {
  const float* x    = (const float*)d_in[0];
  const float* Wih0 = (const float*)d_in[1];
  const float* Whh0 = (const float*)d_in[2];
  const float* bih0 = (const float*)d_in[3];
  const float* bhh0 = (const float*)d_in[4];
  const float* Wih1 = (const float*)d_in[5];
  const float* Whh1 = (const float*)d_in[6];
  const float* bih1 = (const float*)d_in[7];
  const float* bhh1 = (const float*)d_in[8];
  const float* Wfc  = (const float*)d_in[9];
  const float* bfc  = (const float*)d_in[10];

  char* ws = (char*)d_ws;
  ushort_t* wpack = (ushort_t*)(ws + O_WPACK);
  ushort_t* wfcp  = (ushort_t*)(ws + O_WFC);
  float*    bias  = (float*)(ws + O_BIAS);
  ushort_t* seqT  = (ushort_t*)(ws + O_SEQT);
  ushort_t* h_all = (ushort_t*)(ws + O_H);
  float*    xp    = (float*)d_out;      // d_out as scratch until fc_gemm

  hipFuncSetAttribute((const void*)lstm_scan,
                      hipFuncAttributeMaxDynamicSharedMemorySize, SCAN_LDS_BYTES);

  prep_pack<<<4096, 256, 0, stream>>>(Wih0, Whh0, bih0, bhh0,
                                      Wih1, Whh1, bih1, bhh1,
                                      Wfc, wpack, wfcp, bias);
  prep_seq<<<512, 256, 0, stream>>>(x, seqT);
  hipMemsetAsync(h_all, 0xFF, SZ_H, stream);        // sentinel init (every launch)
  xp_gemm<<<dim3(16, 98), 256, 0, stream>>>(wpack, seqT, bias, xp);
  lstm_scan<<<256, 256, SCAN_LDS_BYTES, stream>>>(wpack, bias, h_all, xp);
  dim3 fcg(98, 40);
  fc_gemm<<<fcg, 256, 0, stream>>>(h_all + (size_t)196*64*512, wfcp, bfc,
                                   (float*)d_out);
}